// Round 3
// baseline (465.043 us; speedup 1.0000x reference)
//
#include <hip/hip_runtime.h>
#include <hip/hip_fp16.h>
#include <cstdint>
#include <cstddef>

#define NCLS 50000
#define DIM 512
#define NROW 1024
#define NTN2 196   // ceil(50000/256)

typedef _Float16 half8 __attribute__((ext_vector_type(8)));
typedef float f32x4 __attribute__((ext_vector_type(4)));

#define AS1(p) ((const __attribute__((address_space(1))) void*)(p))
#define AS3(p) ((__attribute__((address_space(3))) void*)(p))

// ---------------- x: convert to fp16 + row inv-norms (exact f32) ----------------
__global__ void prep_x_kernel(const float* __restrict__ x,
                              __half* __restrict__ xh,
                              float* __restrict__ rn)
{
    int row = blockIdx.x;
    int l = threadIdx.x; // 64 threads = 1 wave
    const float4* xr = (const float4*)(x + (size_t)row * DIM);
    __half2* dst = (__half2*)(xh + (size_t)row * DIM);
    float s = 0.f;
#pragma unroll
    for (int i = 0; i < 2; ++i) {
        int idx = l + i * 64;
        float4 v = xr[idx];
        dst[idx * 2]     = __floats2half2_rn(v.x, v.y);
        dst[idx * 2 + 1] = __floats2half2_rn(v.z, v.w);
        s += v.x * v.x + v.y * v.y + v.z * v.z + v.w * v.w;
    }
#pragma unroll
    for (int off = 32; off > 0; off >>= 1) s += __shfl_down(s, off);
    if (l == 0) rn[row] = rsqrtf(s);
}

// ------- W [512][50000] f32 -> Wt [50000][512] fp16, fused col sum-of-squares ----
__global__ void transpose_w_kernel(const float* __restrict__ W,
                                   __half* __restrict__ Wt,
                                   float* __restrict__ part)
{
    __shared__ float tile[64][65];
    __shared__ float cpart[4][64];
    int n0 = blockIdx.x * 64;
    int k0 = blockIdx.y * 64;
    int t = threadIdx.x; // 256
    int f4 = t & 15;
    int kr = t >> 4;
    int n = n0 + f4 * 4;
    bool ok = (n < NCLS);
#pragma unroll
    for (int i = 0; i < 4; ++i) {
        int k = kr + i * 16;
        float4 v = ok ? *(const float4*)(W + (size_t)(k0 + k) * NCLS + n)
                      : make_float4(0.f, 0.f, 0.f, 0.f);
        tile[k][f4 * 4 + 0] = v.x;
        tile[k][f4 * 4 + 1] = v.y;
        tile[k][f4 * 4 + 2] = v.z;
        tile[k][f4 * 4 + 3] = v.w;
    }
    __syncthreads();
#pragma unroll
    for (int i = 0; i < 8; ++i) {
        int idx = t + i * 256;
        int nn = idx >> 5;
        int kp = idx & 31;
        int gn = n0 + nn;
        if (gn < NCLS) {
            __half2 h = __floats2half2_rn(tile[kp * 2][nn], tile[kp * 2 + 1][nn]);
            *(__half2*)(Wt + (size_t)gn * DIM + k0 + kp * 2) = h;
        }
    }
    {
        int nn = t & 63;
        int seg = t >> 6;
        float s = 0.f;
#pragma unroll
        for (int k = 0; k < 16; ++k) {
            float v = tile[seg * 16 + k][nn];
            s += v * v;
        }
        cpart[seg][nn] = s;
        __syncthreads();
        if (t < 64 && n0 + t < NCLS) {
            part[(size_t)blockIdx.y * NCLS + n0 + t] =
                cpart[0][t] + cpart[1][t] + cpart[2][t] + cpart[3][t];
        }
    }
}

__global__ void make_cn_kernel(const float* __restrict__ part, float* __restrict__ cn)
{
    int c = blockIdx.x * 256 + threadIdx.x;
    if (c >= NCLS) return;
    float s = 0.f;
#pragma unroll
    for (int j = 0; j < 8; ++j) s += part[(size_t)j * NCLS + c];
    cn[c] = rsqrtf(s);
}

// ---------------- GEMM + arcface + exp, two-pass, 256x256 / BK=32 / 4-ring ------
// PASS 0: reads y per-element (label detect, writes lab[]), accumulates
//         per-(ntile,row) sums of exp(logit) -> rowpart [NTN2][1024]. No out.
// PASS 1: out[row][col] = exp(logit) * rs[row], label col via lab[].
// 8 waves (2M x 4N), per-wave 128x64. LDS: 4-slot ring x (A 16K + B 16K) = 128 KB.
// Counted vmcnt(8): tile t's loads issued at t-3, never drained fresh.
template<int PASS>
__global__ __launch_bounds__(512, 2) void gemm_arc_kernel(
    const __half* __restrict__ A,
    const __half* __restrict__ Bt,
    const float* __restrict__ rn,
    const float* __restrict__ cn,
    const float* __restrict__ y,
    int* __restrict__ lab,
    const float* __restrict__ rs,
    float* __restrict__ out,
    float* __restrict__ rowpart)
{
    __shared__ __align__(16) char ring[131072];

    const int tid = threadIdx.x;
    const int wid = tid >> 6;
    const int lane = tid & 63;
    const int wm = wid >> 2;   // 0..1
    const int wn = wid & 3;    // 0..3
    const int rl = lane & 15;
    const int g = lane >> 4;   // 0..3
    const int koff = ((g ^ ((rl >> 1) & 3))) * 16; // swizzled 16B k-block, lane-const

    // bijective XCD swizzle: 784 = 8*98; M-fastest (4 mt per nt) for Bt reuse
    const int b = blockIdx.x;
    const int w = (b & 7) * 98 + (b >> 3);
    const int mt = w & 3;
    const int nt = w >> 2;
    const int tileM = mt * 256;
    const int tileN = nt * 256;

    f32x4 acc[8][4] = {};

    // staging: per K-tile (32 k), A = 256x32x2B = 16KB (2 loads), B same.
    const int rA = tid >> 2;                                // row 0..127 in chunk
    const int kbs = ((tid & 3) ^ ((tid >> 3) & 3)) * 8;     // pre-swizzled src k-off (halves)
    auto stage = [&](int t) {
        const int slot = t & 3;
        const int k0 = t * 32;
        char* base = ring + slot * 32768 + wid * 1024;
#pragma unroll
        for (int i = 0; i < 2; ++i) {
            const __half* sa = A + (size_t)(tileM + i * 128 + rA) * DIM + k0 + kbs;
            __builtin_amdgcn_global_load_lds(AS1(sa), AS3(base + i * 8192), 16, 0, 0);
        }
#pragma unroll
        for (int i = 0; i < 2; ++i) {
            int gn = tileN + i * 128 + rA;
            if (gn > NCLS - 1) gn = NCLS - 1;  // clamp N edge (masked in epilogue)
            const __half* sb = Bt + (size_t)gn * DIM + k0 + kbs;
            __builtin_amdgcn_global_load_lds(AS1(sb), AS3(base + 16384 + i * 8192), 16, 0, 0);
        }
    };

    stage(0); stage(1); stage(2);   // 12 loads/thread in flight

#pragma unroll
    for (int t = 0; t < 16; ++t) {
        // wait for tile t's 4 loads (issued at t-3): in-flight 12 -> 8
        if (t < 14)       asm volatile("s_waitcnt vmcnt(8)" ::: "memory");
        else if (t == 14) asm volatile("s_waitcnt vmcnt(4)" ::: "memory");
        else              asm volatile("s_waitcnt vmcnt(0)" ::: "memory");
        __builtin_amdgcn_s_barrier();          // all threads' tile-t data visible
        __builtin_amdgcn_sched_barrier(0);

        const char* aB = ring + (t & 3) * 32768;
        const char* bB = aB + 16384;
        half8 af[8], bf[4];
#pragma unroll
        for (int m = 0; m < 8; ++m) {
            int r = wm * 128 + m * 16 + rl;
            af[m] = *(const half8*)(aB + r * 64 + koff);
        }
#pragma unroll
        for (int n = 0; n < 4; ++n) {
            int r = wn * 64 + n * 16 + rl;
            bf[n] = *(const half8*)(bB + r * 64 + koff);
        }
        if (t + 3 < 16) stage(t + 3);          // overwrites slot holding tile t-1 (consumed)
        __builtin_amdgcn_s_setprio(1);
#pragma unroll
        for (int m = 0; m < 8; ++m)
#pragma unroll
            for (int n = 0; n < 4; ++n)
                acc[m][n] = __builtin_amdgcn_mfma_f32_16x16x32_f16(af[m], bf[n], acc[m][n], 0, 0, 0);
        __builtin_amdgcn_s_setprio(0);
    }

    __syncthreads();   // full drain before LDS reuse (outside hot loop)
    float* rsum = (float*)ring;  // [4][256] overlay

    const float cosM = 0.8775825618903728f;
    const float sinM = 0.4794255386042030f;

#pragma unroll
    for (int m = 0; m < 8; ++m) {
        int row0 = wm * 128 + m * 16 + g * 4;
        int gr0 = tileM + row0;
        float rnv[4]; int labv[4]; float rsv[4];
#pragma unroll
        for (int j = 0; j < 4; ++j) {
            rnv[j] = rn[gr0 + j];
            if (PASS == 1) { labv[j] = lab[gr0 + j]; rsv[j] = rs[gr0 + j]; }
        }
        float rowacc[4] = {0.f, 0.f, 0.f, 0.f};
#pragma unroll
        for (int n = 0; n < 4; ++n) {
            int gc = tileN + wn * 64 + n * 16 + rl;
            bool okc = (gc < NCLS);
            float cnv = okc ? cn[gc] : 0.f;
#pragma unroll
            for (int j = 0; j < 4; ++j) {
                float cv = acc[m][n][j] * rnv[j] * cnv;
                bool isl;
                if (PASS == 0) {
                    float yv = okc ? y[(size_t)(gr0 + j) * NCLS + gc] : 0.f;
                    isl = (yv != 0.f);
                    if (isl) lab[gr0 + j] = gc;   // unique writer per row
                } else {
                    isl = (gc == labv[j]);
                }
                float logit;
                if (isl) {
                    float cc = fminf(fmaxf(cv, -1.f + 1e-7f), 1.f - 1e-7f);
                    logit = 64.f * (cc * cosM - sqrtf(1.f - cc * cc) * sinM);
                } else {
                    logit = 64.f * cv;
                }
                float e = __expf(logit);
                if (PASS == 0) {
                    if (okc) rowacc[j] += e;
                } else {
                    if (okc) out[(size_t)(gr0 + j) * NCLS + gc] = e * rsv[j];
                }
            }
        }
        if (PASS == 0) {
#pragma unroll
            for (int j = 0; j < 4; ++j) {
                float s = rowacc[j];
                s += __shfl_xor(s, 1);
                s += __shfl_xor(s, 2);
                s += __shfl_xor(s, 4);
                s += __shfl_xor(s, 8);
                if (rl == 0) rsum[wn * 256 + row0 + j] = s;
            }
        }
    }
    if (PASS == 0) {
        __syncthreads();
        if (tid < 256) {
            float tot = rsum[tid] + rsum[256 + tid] + rsum[512 + tid] + rsum[768 + tid];
            rowpart[(size_t)nt * NROW + tileM + tid] = tot;
        }
    }
}

// ---------------- reduce per-tile row sums -> 1/rowsum ---------------------------
__global__ void reduce_rs_kernel(const float* __restrict__ rowpart, float* __restrict__ rs)
{
    int row = blockIdx.x * 256 + threadIdx.x; // 4 x 256 = 1024
    float s = 0.f;
    for (int t = 0; t < NTN2; ++t) s += rowpart[(size_t)t * NROW + row];
    rs[row] = 1.f / s;
}

extern "C" void kernel_launch(void* const* d_in, const int* in_sizes, int n_in,
                              void* d_out, int out_size, void* d_ws, size_t ws_size,
                              hipStream_t stream)
{
    const float* x = (const float*)d_in[0]; // [1024][512]
    const float* y = (const float*)d_in[1]; // [1024][50000] one-hot
    const float* W = (const float*)d_in[2]; // [512][50000]
    float* out = (float*)d_out;             // [1024][50000]

    char* ws = (char*)d_ws;
    __half* Wt     = (__half*)(ws);               // 51,200,000 B : W^T fp16 [50000][512]
    __half* xh     = (__half*)(ws + 51200000);    //  1,048,576 B : x fp16
    float* rn      = (float*) (ws + 52248576);    //      4,096 B : row inv-norms
    float* cn      = (float*) (ws + 52252672);    //    200,000 B : col inv-norms
    // part [8][50000] (consumed by make_cn) then reused as rowpart [196][1024]
    float* part    = (float*) (ws + 52452672);    //  1,601,536 B : union(part, rowpart)
    float* rowpart = part;
    int*   lab     = (int*)   (ws + 54054208);    //      4,096 B : labels
    float* rs      = (float*) (ws + 54058304);    //      4,096 B : 1/rowsum

    hipLaunchKernelGGL(prep_x_kernel, dim3(NROW), dim3(64), 0, stream, x, xh, rn);
    hipLaunchKernelGGL(transpose_w_kernel, dim3(782, 8), dim3(256), 0, stream, W, Wt, part);
    hipLaunchKernelGGL(make_cn_kernel, dim3(196), dim3(256), 0, stream, part, cn);
    hipLaunchKernelGGL(gemm_arc_kernel<0>, dim3(8 * 98), dim3(512), 0, stream,
                       xh, Wt, rn, cn, y, lab, rs, out, rowpart);
    hipLaunchKernelGGL(reduce_rs_kernel, dim3(4), dim3(256), 0, stream, rowpart, rs);
    hipLaunchKernelGGL(gemm_arc_kernel<1>, dim3(8 * 98), dim3(512), 0, stream,
                       xh, Wt, rn, cn, y, lab, rs, out, rowpart);
}

// Round 4
// 460.257 us; speedup vs baseline: 1.0104x; 1.0104x over previous
//
#include <hip/hip_runtime.h>
#include <hip/hip_fp16.h>
#include <cstdint>
#include <cstddef>

#define NCLS 50000
#define DIM 512
#define NROW 1024
#define NTN2 196   // ceil(50000/256)

typedef _Float16 half8 __attribute__((ext_vector_type(8)));
typedef float f32x4 __attribute__((ext_vector_type(4)));

#define AS1(p) ((const __attribute__((address_space(1))) void*)(p))
#define AS3(p) ((__attribute__((address_space(3))) void*)(p))

// ---------------- x: convert to fp16 + row inv-norms (exact f32) ----------------
__global__ void prep_x_kernel(const float* __restrict__ x,
                              __half* __restrict__ xh,
                              float* __restrict__ rn)
{
    int row = blockIdx.x;
    int l = threadIdx.x; // 64 threads = 1 wave
    const float4* xr = (const float4*)(x + (size_t)row * DIM);
    __half2* dst = (__half2*)(xh + (size_t)row * DIM);
    float s = 0.f;
#pragma unroll
    for (int i = 0; i < 2; ++i) {
        int idx = l + i * 64;
        float4 v = xr[idx];
        dst[idx * 2]     = __floats2half2_rn(v.x, v.y);
        dst[idx * 2 + 1] = __floats2half2_rn(v.z, v.w);
        s += v.x * v.x + v.y * v.y + v.z * v.z + v.w * v.w;
    }
#pragma unroll
    for (int off = 32; off > 0; off >>= 1) s += __shfl_down(s, off);
    if (l == 0) rn[row] = rsqrtf(s);
}

// ------- W [512][50000] f32 -> Wt [50000][512] fp16, fused col sum-of-squares ----
__global__ void transpose_w_kernel(const float* __restrict__ W,
                                   __half* __restrict__ Wt,
                                   float* __restrict__ part)
{
    __shared__ float tile[64][65];
    __shared__ float cpart[4][64];
    int n0 = blockIdx.x * 64;
    int k0 = blockIdx.y * 64;
    int t = threadIdx.x; // 256
    int f4 = t & 15;
    int kr = t >> 4;
    int n = n0 + f4 * 4;
    bool ok = (n < NCLS);
#pragma unroll
    for (int i = 0; i < 4; ++i) {
        int k = kr + i * 16;
        float4 v = ok ? *(const float4*)(W + (size_t)(k0 + k) * NCLS + n)
                      : make_float4(0.f, 0.f, 0.f, 0.f);
        tile[k][f4 * 4 + 0] = v.x;
        tile[k][f4 * 4 + 1] = v.y;
        tile[k][f4 * 4 + 2] = v.z;
        tile[k][f4 * 4 + 3] = v.w;
    }
    __syncthreads();
#pragma unroll
    for (int i = 0; i < 8; ++i) {
        int idx = t + i * 256;
        int nn = idx >> 5;
        int kp = idx & 31;
        int gn = n0 + nn;
        if (gn < NCLS) {
            __half2 h = __floats2half2_rn(tile[kp * 2][nn], tile[kp * 2 + 1][nn]);
            *(__half2*)(Wt + (size_t)gn * DIM + k0 + kp * 2) = h;
        }
    }
    {
        int nn = t & 63;
        int seg = t >> 6;
        float s = 0.f;
#pragma unroll
        for (int k = 0; k < 16; ++k) {
            float v = tile[seg * 16 + k][nn];
            s += v * v;
        }
        cpart[seg][nn] = s;
        __syncthreads();
        if (t < 64 && n0 + t < NCLS) {
            part[(size_t)blockIdx.y * NCLS + n0 + t] =
                cpart[0][t] + cpart[1][t] + cpart[2][t] + cpart[3][t];
        }
    }
}

__global__ void make_cn_kernel(const float* __restrict__ part, float* __restrict__ cn)
{
    int c = blockIdx.x * 256 + threadIdx.x;
    if (c >= NCLS) return;
    float s = 0.f;
#pragma unroll
    for (int j = 0; j < 8; ++j) s += part[(size_t)j * NCLS + c];
    cn[c] = rsqrtf(s);
}

// ---------------- GEMM + arcface + exp, two-pass, 256x256 / BK=32 / 4-ring ------
// Rolled K-loop (no address-precompute register explosion), counted vmcnt(8),
// raw s_barrier once per tile, stage issued right after barrier, MFMA in two
// 16-MFMA clusters to halve fragment liveness.
template<int PASS>
__global__ __launch_bounds__(512, 2) void gemm_arc_kernel(
    const __half* __restrict__ A,
    const __half* __restrict__ Bt,
    const float* __restrict__ rn,
    const float* __restrict__ cn,
    const float* __restrict__ y,
    int* __restrict__ lab,
    const float* __restrict__ rs,
    float* __restrict__ out,
    float* __restrict__ rowpart)
{
    __shared__ __align__(16) char ring[131072];

    const int tid = threadIdx.x;
    const int wid = tid >> 6;
    const int lane = tid & 63;
    const int wm = wid >> 2;   // 0..1
    const int wn = wid & 3;    // 0..3
    const int rl = lane & 15;
    const int g = lane >> 4;   // 0..3 (k-block)
    const int koff = (g ^ ((rl >> 1) & 3)) * 16; // XOR de-swizzle on read

    // bijective XCD swizzle: 784 = 8*98; M-fastest (4 mt per nt) for Bt reuse
    const int b = blockIdx.x;
    const int w = (b & 7) * 98 + (b >> 3);
    const int mt = w & 3;
    const int nt = w >> 2;
    const int tileM = mt * 256;
    const int tileN = nt * 256;

    f32x4 acc[8][4] = {};

    // staging bases: 4 pointers, advanced by t*32 halves per tile
    const int rA = tid >> 2;                             // row 0..127 within half
    const int kbs = ((tid & 3) ^ ((tid >> 3) & 3)) * 8;  // pre-swizzled src halves
    const __half* aS0 = A + (size_t)(tileM + rA) * DIM + kbs;
    const __half* aS1 = aS0 + (size_t)128 * DIM;
    int gn0 = tileN + rA;       if (gn0 > NCLS - 1) gn0 = NCLS - 1;
    int gn1 = tileN + 128 + rA; if (gn1 > NCLS - 1) gn1 = NCLS - 1;
    const __half* bS0 = Bt + (size_t)gn0 * DIM + kbs;
    const __half* bS1 = Bt + (size_t)gn1 * DIM + kbs;

    auto stage = [&](int t) {
        char* base = ring + (t & 3) * 32768 + wid * 1024;
        const int ko = t * 32;
        __builtin_amdgcn_global_load_lds(AS1(aS0 + ko), AS3(base), 16, 0, 0);
        __builtin_amdgcn_global_load_lds(AS1(aS1 + ko), AS3(base + 8192), 16, 0, 0);
        __builtin_amdgcn_global_load_lds(AS1(bS0 + ko), AS3(base + 16384), 16, 0, 0);
        __builtin_amdgcn_global_load_lds(AS1(bS1 + ko), AS3(base + 24576), 16, 0, 0);
    };

    stage(0); stage(1); stage(2);   // 12 loads/thread in flight

    // per-thread LDS read offsets (A: rows wm*128+m*16+rl; B: rows wn*64+n*16+rl)
    const int aOff = wm * 8192 + rl * 64 + koff;                         // + m*1024
    const int bOff = 16384 + (wn >> 1) * 8192 + ((wn & 1) * 64 + rl) * 64 + koff; // + n*1024

#pragma unroll 1
    for (int t = 0; t < 16; ++t) {
        if (t < 14)      asm volatile("s_waitcnt vmcnt(8)" ::: "memory");
        else if (t == 14) asm volatile("s_waitcnt vmcnt(4)" ::: "memory");
        else             asm volatile("s_waitcnt vmcnt(0)" ::: "memory");
        __builtin_amdgcn_s_barrier();          // tile t's data visible to all waves
        __builtin_amdgcn_sched_barrier(0);

        if (t < 13) stage(t + 3);              // overwrites slot of tile t-1 (consumed)

        const char* sb = ring + (t & 3) * 32768;
        half8 bf[4], af[4];
#pragma unroll
        for (int n = 0; n < 4; ++n)
            bf[n] = *(const half8*)(sb + bOff + n * 1024);
        // m-half 0
#pragma unroll
        for (int m = 0; m < 4; ++m)
            af[m] = *(const half8*)(sb + aOff + m * 1024);
        __builtin_amdgcn_s_setprio(1);
#pragma unroll
        for (int m = 0; m < 4; ++m)
#pragma unroll
            for (int n = 0; n < 4; ++n)
                acc[m][n] = __builtin_amdgcn_mfma_f32_16x16x32_f16(af[m], bf[n], acc[m][n], 0, 0, 0);
        __builtin_amdgcn_s_setprio(0);
        // m-half 1
#pragma unroll
        for (int m = 0; m < 4; ++m)
            af[m] = *(const half8*)(sb + aOff + (m + 4) * 1024);
        __builtin_amdgcn_s_setprio(1);
#pragma unroll
        for (int m = 0; m < 4; ++m)
#pragma unroll
            for (int n = 0; n < 4; ++n)
                acc[m + 4][n] = __builtin_amdgcn_mfma_f32_16x16x32_f16(af[m], bf[n], acc[m + 4][n], 0, 0, 0);
        __builtin_amdgcn_s_setprio(0);
    }

    __syncthreads();   // full drain before LDS reuse (outside hot loop)
    float* rsum = (float*)ring;  // [4][256] overlay

    const float cosM = 0.8775825618903728f;
    const float sinM = 0.4794255386042030f;

#pragma unroll
    for (int m = 0; m < 8; ++m) {
        int row0 = wm * 128 + m * 16 + g * 4;
        int gr0 = tileM + row0;
        float rnv[4]; int labv[4]; float rsv[4];
#pragma unroll
        for (int j = 0; j < 4; ++j) {
            rnv[j] = rn[gr0 + j];
            if (PASS == 1) { labv[j] = lab[gr0 + j]; rsv[j] = rs[gr0 + j]; }
        }
        float rowacc[4] = {0.f, 0.f, 0.f, 0.f};
#pragma unroll
        for (int n = 0; n < 4; ++n) {
            int gc = tileN + wn * 64 + n * 16 + rl;
            bool okc = (gc < NCLS);
            float cnv = okc ? cn[gc] : 0.f;
#pragma unroll
            for (int j = 0; j < 4; ++j) {
                float cv = acc[m][n][j] * rnv[j] * cnv;
                bool isl;
                if (PASS == 0) {
                    float yv = okc ? y[(size_t)(gr0 + j) * NCLS + gc] : 0.f;
                    isl = (yv != 0.f);
                    if (isl) lab[gr0 + j] = gc;   // unique writer per row
                } else {
                    isl = (gc == labv[j]);
                }
                float logit;
                if (isl) {
                    float cc = fminf(fmaxf(cv, -1.f + 1e-7f), 1.f - 1e-7f);
                    logit = 64.f * (cc * cosM - sqrtf(1.f - cc * cc) * sinM);
                } else {
                    logit = 64.f * cv;
                }
                float e = __expf(logit);
                if (PASS == 0) {
                    if (okc) rowacc[j] += e;
                } else {
                    if (okc) out[(size_t)(gr0 + j) * NCLS + gc] = e * rsv[j];
                }
            }
        }
        if (PASS == 0) {
#pragma unroll
            for (int j = 0; j < 4; ++j) {
                float s = rowacc[j];
                s += __shfl_xor(s, 1);
                s += __shfl_xor(s, 2);
                s += __shfl_xor(s, 4);
                s += __shfl_xor(s, 8);
                if (rl == 0) rsum[wn * 256 + row0 + j] = s;
            }
        }
    }
    if (PASS == 0) {
        __syncthreads();
        if (tid < 256) {
            float tot = rsum[tid] + rsum[256 + tid] + rsum[512 + tid] + rsum[768 + tid];
            rowpart[(size_t)nt * NROW + tileM + tid] = tot;
        }
    }
}

// ---------------- reduce per-tile row sums -> 1/rowsum ---------------------------
__global__ void reduce_rs_kernel(const float* __restrict__ rowpart, float* __restrict__ rs)
{
    int row = blockIdx.x * 256 + threadIdx.x; // 4 x 256 = 1024
    float s = 0.f;
    for (int t = 0; t < NTN2; ++t) s += rowpart[(size_t)t * NROW + row];
    rs[row] = 1.f / s;
}

extern "C" void kernel_launch(void* const* d_in, const int* in_sizes, int n_in,
                              void* d_out, int out_size, void* d_ws, size_t ws_size,
                              hipStream_t stream)
{
    const float* x = (const float*)d_in[0]; // [1024][512]
    const float* y = (const float*)d_in[1]; // [1024][50000] one-hot
    const float* W = (const float*)d_in[2]; // [512][50000]
    float* out = (float*)d_out;             // [1024][50000]

    char* ws = (char*)d_ws;
    __half* Wt     = (__half*)(ws);               // 51,200,000 B : W^T fp16 [50000][512]
    __half* xh     = (__half*)(ws + 51200000);    //  1,048,576 B : x fp16
    float* rn      = (float*) (ws + 52248576);    //      4,096 B : row inv-norms
    float* cn      = (float*) (ws + 52252672);    //    200,000 B : col inv-norms
    // part [8][50000] (consumed by make_cn) then reused as rowpart [196][1024]
    float* part    = (float*) (ws + 52452672);    //  1,601,536 B : union(part, rowpart)
    float* rowpart = part;
    int*   lab     = (int*)   (ws + 54054208);    //      4,096 B : labels
    float* rs      = (float*) (ws + 54058304);    //      4,096 B : 1/rowsum

    hipLaunchKernelGGL(prep_x_kernel, dim3(NROW), dim3(64), 0, stream, x, xh, rn);
    hipLaunchKernelGGL(transpose_w_kernel, dim3(782, 8), dim3(256), 0, stream, W, Wt, part);
    hipLaunchKernelGGL(make_cn_kernel, dim3(196), dim3(256), 0, stream, part, cn);
    hipLaunchKernelGGL(gemm_arc_kernel<0>, dim3(8 * 98), dim3(512), 0, stream,
                       xh, Wt, rn, cn, y, lab, rs, out, rowpart);
    hipLaunchKernelGGL(reduce_rs_kernel, dim3(4), dim3(256), 0, stream, rowpart, rs);
    hipLaunchKernelGGL(gemm_arc_kernel<1>, dim3(8 * 98), dim3(512), 0, stream,
                       xh, Wt, rn, cn, y, lab, rs, out, rowpart);
}

// Round 5
// 257.691 us; speedup vs baseline: 1.8047x; 1.7861x over previous
//
#include <hip/hip_runtime.h>
#include <hip/hip_fp16.h>
#include <cstdint>
#include <cstddef>

#define NCLS 50000
#define DIM 512
#define NROW 1024
#define NTN 391   // ceil(50000/128)

typedef _Float16 half8 __attribute__((ext_vector_type(8)));
typedef float f32x4 __attribute__((ext_vector_type(4)));

#define AS1(p) ((const __attribute__((address_space(1))) void*)(p))
#define AS3(p) ((__attribute__((address_space(3))) void*)(p))

// ---------------- x: convert to fp16 + row inv-norms (exact f32) ----------------
__global__ void prep_x_kernel(const float* __restrict__ x,
                              __half* __restrict__ xh,
                              float* __restrict__ rn)
{
    int row = blockIdx.x;
    int l = threadIdx.x; // 64 threads = 1 wave
    const float4* xr = (const float4*)(x + (size_t)row * DIM);
    __half2* dst = (__half2*)(xh + (size_t)row * DIM);
    float s = 0.f;
#pragma unroll
    for (int i = 0; i < 2; ++i) {
        int idx = l + i * 64;
        float4 v = xr[idx];
        dst[idx * 2]     = __floats2half2_rn(v.x, v.y);
        dst[idx * 2 + 1] = __floats2half2_rn(v.z, v.w);
        s += v.x * v.x + v.y * v.y + v.z * v.z + v.w * v.w;
    }
#pragma unroll
    for (int off = 32; off > 0; off >>= 1) s += __shfl_down(s, off);
    if (l == 0) rn[row] = rsqrtf(s);
}

// ------- W [512][50000] f32 -> Wt [50000][512] fp16, fused col sum-of-squares ----
__global__ void transpose_w_kernel(const float* __restrict__ W,
                                   __half* __restrict__ Wt,
                                   float* __restrict__ part)
{
    __shared__ float tile[64][65];
    __shared__ float cpart[4][64];
    int n0 = blockIdx.x * 64;
    int k0 = blockIdx.y * 64;
    int t = threadIdx.x; // 256
    int f4 = t & 15;
    int kr = t >> 4;
    int n = n0 + f4 * 4;
    bool ok = (n < NCLS);
#pragma unroll
    for (int i = 0; i < 4; ++i) {
        int k = kr + i * 16;
        float4 v = ok ? *(const float4*)(W + (size_t)(k0 + k) * NCLS + n)
                      : make_float4(0.f, 0.f, 0.f, 0.f);
        tile[k][f4 * 4 + 0] = v.x;
        tile[k][f4 * 4 + 1] = v.y;
        tile[k][f4 * 4 + 2] = v.z;
        tile[k][f4 * 4 + 3] = v.w;
    }
    __syncthreads();
#pragma unroll
    for (int i = 0; i < 8; ++i) {
        int idx = t + i * 256;
        int nn = idx >> 5;
        int kp = idx & 31;
        int gn = n0 + nn;
        if (gn < NCLS) {
            __half2 h = __floats2half2_rn(tile[kp * 2][nn], tile[kp * 2 + 1][nn]);
            *(__half2*)(Wt + (size_t)gn * DIM + k0 + kp * 2) = h;
        }
    }
    {
        int nn = t & 63;
        int seg = t >> 6;
        float s = 0.f;
#pragma unroll
        for (int k = 0; k < 16; ++k) {
            float v = tile[seg * 16 + k][nn];
            s += v * v;
        }
        cpart[seg][nn] = s;
        __syncthreads();
        if (t < 64 && n0 + t < NCLS) {
            part[(size_t)blockIdx.y * NCLS + n0 + t] =
                cpart[0][t] + cpart[1][t] + cpart[2][t] + cpart[3][t];
        }
    }
}

__global__ void make_cn_kernel(const float* __restrict__ part, float* __restrict__ cn)
{
    int c = blockIdx.x * 256 + threadIdx.x;
    if (c >= NCLS) return;
    float s = 0.f;
#pragma unroll
    for (int j = 0; j < 8; ++j) s += part[(size_t)j * NCLS + c];
    cn[c] = rsqrtf(s);
}

// ---------------- labels from one-hot y -----------------------------------------
__global__ void find_labels_kernel(const float4* __restrict__ y4, int* __restrict__ lab)
{
    int i4 = blockIdx.x * 256 + threadIdx.x; // exactly 12,800,000 threads
    float4 v = y4[i4];
    if (v.x != 0.f || v.y != 0.f || v.z != 0.f || v.w != 0.f) {
        long base = (long)i4 * 4;
        if (v.x != 0.f) { long i = base + 0; lab[i / NCLS] = (int)(i % NCLS); }
        if (v.y != 0.f) { long i = base + 1; lab[i / NCLS] = (int)(i % NCLS); }
        if (v.z != 0.f) { long i = base + 2; lab[i / NCLS] = (int)(i % NCLS); }
        if (v.w != 0.f) { long i = base + 3; lab[i / NCLS] = (int)(i % NCLS); }
    }
}

// ---------------- GEMM + arcface + exp, two-pass --------------------------------
// m97-exact structure: 128x128 tile, BK=64, 4 waves (2x2), SINGLE 32 KB LDS
// buffer, stage->sync->compute->sync, 4 blocks/CU for cross-block latency hiding.
template<int PASS>
__global__ __launch_bounds__(256, 4) void gemm_arc_kernel(
    const __half* __restrict__ A,
    const __half* __restrict__ Bt,
    const float* __restrict__ rn,
    const float* __restrict__ cn,
    const int* __restrict__ lab,
    const float* __restrict__ rs,
    float* __restrict__ out,
    float* __restrict__ rowpart)
{
    __shared__ __align__(16) __half As[128 * 64];
    __shared__ __align__(16) __half Bs[128 * 64];
    __shared__ float rsum[2][128];

    const int tid = threadIdx.x;
    const int wid = tid >> 6;
    const int lane = tid & 63;
    const int wm = wid >> 1;
    const int wn = wid & 1;

    // bijective XCD swizzle: 3128 = 8 * 391; M-fastest (8 mt per nt) for Bt reuse
    const int b = blockIdx.x;
    const int w = (b & 7) * NTN + (b >> 3);
    const int mt = w & 7;
    const int nt = w >> 3;
    const int tileM = mt * 128;
    const int tileN = nt * 128;

    const int srow = lane >> 3;            // 0..7
    const int sblk = (lane & 7) ^ srow;    // pre-swizzled global 16B-block

    f32x4 acc[4][4] = {};

    auto stage = [&](int k0) {
#pragma unroll
        for (int c = 0; c < 4; ++c) {
            int chunk = wid * 4 + c;       // wave-uniform
            int row = chunk * 8 + srow;    // 0..127
            const __half* sa = A + (size_t)(tileM + row) * DIM + k0 + sblk * 8;
            __builtin_amdgcn_global_load_lds(AS1(sa), AS3((char*)As + chunk * 1024), 16, 0, 0);
            int gn = tileN + row;
            if (gn > NCLS - 1) gn = NCLS - 1; // clamp N edge (masked later)
            const __half* sb = Bt + (size_t)gn * DIM + k0 + sblk * 8;
            __builtin_amdgcn_global_load_lds(AS1(sb), AS3((char*)Bs + chunk * 1024), 16, 0, 0);
        }
    };

    auto compute = [&]() {
        const int krow = lane >> 4; // 0..3
        const int rl = lane & 15;
#pragma unroll
        for (int kk = 0; kk < 2; ++kk) {
            half8 af[4], bf[4];
#pragma unroll
            for (int m = 0; m < 4; ++m) {
                int r = wm * 64 + m * 16 + rl;
                int kb = (kk * 4 + krow) ^ (r & 7); // XOR de-swizzle on read
                af[m] = *(const half8*)((const char*)As + r * 128 + kb * 16);
            }
#pragma unroll
            for (int n = 0; n < 4; ++n) {
                int r = wn * 64 + n * 16 + rl;
                int kb = (kk * 4 + krow) ^ (r & 7);
                bf[n] = *(const half8*)((const char*)Bs + r * 128 + kb * 16);
            }
#pragma unroll
            for (int m = 0; m < 4; ++m)
#pragma unroll
                for (int n = 0; n < 4; ++n)
                    acc[m][n] = __builtin_amdgcn_mfma_f32_16x16x32_f16(af[m], bf[n], acc[m][n], 0, 0, 0);
        }
    };

    // m97 loop: single buffer, drain hidden by 4 co-resident blocks
#pragma unroll 1
    for (int k0 = 0; k0 < DIM; k0 += 64) {
        stage(k0);
        __syncthreads();
        compute();
        __syncthreads();
    }

    // epilogue
    const float cosM = 0.8775825618903728f;
    const float sinM = 0.4794255386042030f;
    const int col_l = lane & 15;
    const int rgrp = lane >> 4;

#pragma unroll
    for (int m = 0; m < 4; ++m) {
        int gr0 = tileM + wm * 64 + m * 16 + rgrp * 4;
        float rnv[4]; int labv[4]; float rsv[4];
#pragma unroll
        for (int r = 0; r < 4; ++r) {
            rnv[r] = rn[gr0 + r];
            labv[r] = lab[gr0 + r];
            if (PASS == 1) rsv[r] = rs[gr0 + r];
        }
        float rowacc[4] = {0.f, 0.f, 0.f, 0.f};
#pragma unroll
        for (int n = 0; n < 4; ++n) {
            int gc = tileN + wn * 64 + n * 16 + col_l;
            bool okc = (gc < NCLS);
            float cnv = okc ? cn[gc] : 0.f;
#pragma unroll
            for (int r = 0; r < 4; ++r) {
                float cv = acc[m][n][r] * rnv[r] * cnv;
                float logit;
                if (gc == labv[r]) {
                    float cc = fminf(fmaxf(cv, -1.f + 1e-7f), 1.f - 1e-7f);
                    logit = 64.f * (cc * cosM - sqrtf(1.f - cc * cc) * sinM);
                } else {
                    logit = 64.f * cv;
                }
                float e = __expf(logit);
                if (PASS == 0) {
                    if (okc) rowacc[r] += e;
                } else {
                    if (okc) out[(size_t)(gr0 + r) * NCLS + gc] = e * rsv[r];
                }
            }
        }
        if (PASS == 0) {
#pragma unroll
            for (int r = 0; r < 4; ++r) {
                float s = rowacc[r];
                s += __shfl_xor(s, 1);
                s += __shfl_xor(s, 2);
                s += __shfl_xor(s, 4);
                s += __shfl_xor(s, 8);
                if (col_l == 0) rsum[wn][wm * 64 + m * 16 + rgrp * 4 + r] = s;
            }
        }
    }
    if (PASS == 0) {
        __syncthreads();
        if (tid < 128) {
            float tot = rsum[0][tid] + rsum[1][tid];
            rowpart[(size_t)nt * NROW + tileM + tid] = tot;
        }
    }
}

// ---------------- reduce per-tile row sums -> 1/rowsum ---------------------------
__global__ void reduce_rs_kernel(const float* __restrict__ rowpart, float* __restrict__ rs)
{
    int row = blockIdx.x * 256 + threadIdx.x; // 4 x 256 = 1024
    float s = 0.f;
    for (int t = 0; t < NTN; ++t) s += rowpart[(size_t)t * NROW + row];
    rs[row] = 1.f / s;
}

extern "C" void kernel_launch(void* const* d_in, const int* in_sizes, int n_in,
                              void* d_out, int out_size, void* d_ws, size_t ws_size,
                              hipStream_t stream)
{
    const float* x = (const float*)d_in[0]; // [1024][512]
    const float* y = (const float*)d_in[1]; // [1024][50000] one-hot
    const float* W = (const float*)d_in[2]; // [512][50000]
    float* out = (float*)d_out;             // [1024][50000]

    char* ws = (char*)d_ws;
    __half* Wt     = (__half*)(ws);               // 51,200,000 B : W^T fp16 [50000][512]
    __half* xh     = (__half*)(ws + 51200000);    //  1,048,576 B : x fp16
    float* rn      = (float*) (ws + 52248576);    //      4,096 B : row inv-norms
    float* cn      = (float*) (ws + 52252672);    //    200,000 B : col inv-norms
    // part [8][50000] (consumed by make_cn) then reused as rowpart [391][1024]
    float* part    = (float*) (ws + 52452672);    //  1,601,536 B : union(part, rowpart)
    float* rowpart = part;
    int*   lab     = (int*)   (ws + 54054208);    //      4,096 B : labels
    float* rs      = (float*) (ws + 54058304);    //      4,096 B : 1/rowsum

    hipLaunchKernelGGL(prep_x_kernel, dim3(NROW), dim3(64), 0, stream, x, xh, rn);
    hipLaunchKernelGGL(transpose_w_kernel, dim3(782, 8), dim3(256), 0, stream, W, Wt, part);
    hipLaunchKernelGGL(make_cn_kernel, dim3(196), dim3(256), 0, stream, part, cn);
    hipLaunchKernelGGL(find_labels_kernel, dim3(50000), dim3(256), 0, stream, (const float4*)y, lab);
    hipLaunchKernelGGL(gemm_arc_kernel<0>, dim3(8 * NTN), dim3(256), 0, stream,
                       xh, Wt, rn, cn, lab, rs, out, rowpart);
    hipLaunchKernelGGL(reduce_rs_kernel, dim3(4), dim3(256), 0, stream, rowpart, rs);
    hipLaunchKernelGGL(gemm_arc_kernel<1>, dim3(8 * NTN), dim3(256), 0, stream,
                       xh, Wt, rn, cn, lab, rs, out, rowpart);
}